// Round 11
// baseline (220.441 us; speedup 1.0000x reference)
//
#include <hip/hip_runtime.h>
#include <hip/hip_fp16.h>

// GCN encoder on MI355X. CSR (counting sort by dst) + fused gather aggregation.
// fp16 activations; 4-byte edge records {w:fp16 | src:u16} (N=50000 < 2^16);
// scalar (wave-uniform) record loads; ONE edge row per load instruction;
// 16 row loads in flight. gather1 is at the per-XCD L2-miss concurrency floor
// (rounds 8/10 null probes + byte-scaling model). This round: dispatch-count
// 10 -> 7 (prep merge, last-block scan finalize), vectorized hist, nt fill
// stores. Cooperative grid.sync rejected (round 9: ~70us/sync).

#define K_DIM 128

typedef _Float16 f16x8 __attribute__((ext_vector_type(8)));
typedef _Float16 f16x4 __attribute__((ext_vector_type(4)));
typedef float f32x4 __attribute__((ext_vector_type(4)));

__device__ __forceinline__ float wbits(unsigned int r) {
    return __half2float(__ushort_as_half((unsigned short)(r >> 16)));
}

// ---------- prep: zero counts + done + edge pad, W1 -> W1^T fp16 ----------
__global__ __launch_bounds__(256) void prep_kernel(int* counts, int* done,
                                                   unsigned int* edges,
                                                   const float* __restrict__ W1,
                                                   _Float16* WT, int N, int E) {
    int idx = blockIdx.x * 256 + threadIdx.x;
    if (idx < N) counts[idx] = 0;
    if (blockIdx.x == 0) {
        if (threadIdx.x < 64) edges[E + threadIdx.x] = 0;
        if (threadIdx.x == 64) *done = 0;
    }
    if (idx < 128 * 128) {
        int k = idx >> 7, j = idx & 127;
        WT[j * 128 + k] = (_Float16)W1[idx];
    }
}

// ---------- hist: 4 edges/thread, int4 loads ----------
__global__ __launch_bounds__(256) void hist_kernel(const int* __restrict__ dst,
                                                   int* counts, int E) {
    int base = (blockIdx.x * 256 + threadIdx.x) * 4;
    if (base + 4 <= E) {
        int4 d = *(const int4*)(dst + base);
        atomicAdd(&counts[d.x], 1);
        atomicAdd(&counts[d.y], 1);
        atomicAdd(&counts[d.z], 1);
        atomicAdd(&counts[d.w], 1);
    } else {
        for (int i = base; i < E; ++i) atomicAdd(&counts[dst[i]], 1);
    }
}

// ---------- scan: block-local exclusive scan + dinv; LAST block scans partials ----------
__global__ __launch_bounds__(256) void scan_block_kernel(const int* __restrict__ counts,
                                                         int* row_ptr, int* partials,
                                                         float* dinv, int* done,
                                                         int N, int nchunks) {
    __shared__ int sm[256];
    __shared__ int is_last;
    int t = threadIdx.x;
    int i = blockIdx.x * 256 + t;
    int v = (i < N) ? counts[i] : 0;
    if (i < N) dinv[i] = rsqrtf((float)(v + 1));  // +1 self-loop
    sm[t] = v;
    __syncthreads();
    for (int off = 1; off < 256; off <<= 1) {
        int add = (t >= off) ? sm[t - off] : 0;
        __syncthreads();
        sm[t] += add;
        __syncthreads();
    }
    if (i < N) row_ptr[i] = sm[t] - v;  // block-local exclusive
    if (t == 255) atomicExch(&partials[blockIdx.x], sm[255]);
    __syncthreads();
    if (t == 0) {
        __threadfence();  // release partials before signaling
        int old = atomicAdd(done, 1);
        is_last = (old == (int)gridDim.x - 1);
    }
    __syncthreads();
    if (!is_last) return;

    // last block: exclusive scan of partials (device-scope atomics, acquire fence)
    __threadfence();
    int pv = (t < nchunks) ? atomicAdd(&partials[t], 0) : 0;
    sm[t] = pv;
    __syncthreads();
    for (int off = 1; off < 256; off <<= 1) {
        int add = (t >= off) ? sm[t - off] : 0;
        __syncthreads();
        sm[t] += add;
        __syncthreads();
    }
    if (t < nchunks) atomicExch(&partials[t], sm[t] - pv);
}

// ---------- fill: global pos = block-local cursor + partials[d>>8] ----------
__global__ __launch_bounds__(256) void fill_kernel(const int* __restrict__ src,
                                                   const int* __restrict__ dst,
                                                   const float* __restrict__ dinv,
                                                   int* row_ptr,
                                                   const int* __restrict__ partials,
                                                   unsigned int* edges, int E) {
    int i = blockIdx.x * 256 + threadIdx.x;
    if (i < E) {
        int d = dst[i];
        int s = src[i];
        int pos = atomicAdd(&row_ptr[d], 1) + partials[d >> 8];
        float w = dinv[s] * dinv[d];
        unsigned int rec = ((unsigned int)__half_as_ushort(__float2half_rn(w)) << 16)
                         | (unsigned int)s;
        __builtin_nontemporal_store(rec, &edges[pos]);
    }
}

// ---------- GEMM1 (MFMA): h1 = X @ W1, f16 out ----------
__global__ __launch_bounds__(256) void gemm1_mfma_kernel(const float* __restrict__ X,
                                                         const _Float16* __restrict__ WT,
                                                         __half* __restrict__ H, int N) {
    __shared__ _Float16 As[64][136];

    int row0 = blockIdx.x * 64;
    {
        int r = threadIdx.x >> 2;
        int c0 = (threadIdx.x & 3) * 32;
        int row = row0 + r;
        if (row < N) {
            const float4* srcp = (const float4*)(X + (size_t)row * 128 + c0);
#pragma unroll
            for (int i = 0; i < 8; ++i) {
                float4 v = srcp[i];
                f16x4 h = {(_Float16)v.x, (_Float16)v.y, (_Float16)v.z, (_Float16)v.w};
                *(f16x4*)&As[r][c0 + 4 * i] = h;
            }
        } else {
            f16x4 z = {};
#pragma unroll
            for (int i = 0; i < 8; ++i) *(f16x4*)&As[r][c0 + 4 * i] = z;
        }
    }
    __syncthreads();

    int wave = threadIdx.x >> 6;
    int lane = threadIdx.x & 63;
    int l15 = lane & 15;
    int k0 = (lane >> 4) * 8;
    int arow = wave * 16 + l15;

    f32x4 acc[8] = {};
#pragma unroll
    for (int ks = 0; ks < 4; ++ks) {
        f16x8 a = *(const f16x8*)&As[arow][ks * 32 + k0];
#pragma unroll
        for (int t = 0; t < 8; ++t) {
            f16x8 b = *(const f16x8*)(WT + (size_t)(t * 16 + l15) * 128 + ks * 32 + k0);
            acc[t] = __builtin_amdgcn_mfma_f32_16x16x32_f16(a, b, acc[t], 0, 0, 0);
        }
    }

    int rbase = row0 + wave * 16 + (lane >> 4) * 4;
#pragma unroll
    for (int t = 0; t < 8; ++t) {
#pragma unroll
        for (int r = 0; r < 4; ++r) {
            int row = rbase + r;
            if (row < N) H[(size_t)row * 128 + t * 16 + l15] = __float2half(acc[t][r]);
        }
    }
}

// ---------- gather1 fused: agg(h1) -> +b1 -> LN -> ReLU -> @W2 -> h3 (fp16) ----------
__global__ __launch_bounds__(256) void gather1_fused_kernel(
    const __half* __restrict__ h1, const float* __restrict__ dinv,
    const int* __restrict__ row_ptr, const int* __restrict__ counts,
    const int* __restrict__ partials, const unsigned int* __restrict__ edges,
    const float* __restrict__ b1, const float* __restrict__ g1,
    const float* __restrict__ beta1, const float* __restrict__ W2,
    __half* __restrict__ h3, int N) {
    __shared__ float lds[4][K_DIM];
    int wave = threadIdx.x >> 6;
    int lane = threadIdx.x & 63;
    int node = blockIdx.x * 4 + wave;
    if (node >= N) return;

    float dd = dinv[node];
    float2 acc = __half22float2(((const __half2*)(h1 + (size_t)node * 128))[lane]);
    acc.x *= dd * dd; acc.y *= dd * dd;

    int end = row_ptr[node] + partials[node >> 8];
    int beg = end - counts[node];
    beg = __builtin_amdgcn_readfirstlane(beg);
    end = __builtin_amdgcn_readfirstlane(end);

    int e = beg;
    for (; e + 16 <= end; e += 16) {
        unsigned int rec[16];
#pragma unroll
        for (int i = 0; i < 16; ++i) rec[i] = edges[e + i];   // uniform -> s_load
        __half2 v[16];
#pragma unroll
        for (int i = 0; i < 16; ++i)
            v[i] = ((const __half2*)(h1 + (size_t)(rec[i] & 0xFFFFu) * 128))[lane];
#pragma unroll
        for (int i = 0; i < 16; ++i) {
            float w = wbits(rec[i]);
            float2 f = __half22float2(v[i]);
            acc.x = fmaf(f.x, w, acc.x);
            acc.y = fmaf(f.y, w, acc.y);
        }
    }
    for (; e < end; e += 8) {
        unsigned int rec[8];
#pragma unroll
        for (int i = 0; i < 8; ++i) rec[i] = edges[e + i];
        __half2 v[8];
#pragma unroll
        for (int i = 0; i < 8; ++i)
            v[i] = ((const __half2*)(h1 + (size_t)(rec[i] & 0xFFFFu) * 128))[lane];
#pragma unroll
        for (int i = 0; i < 8; ++i) {
            float w = (e + i < end) ? wbits(rec[i]) : 0.0f;
            float2 f = __half22float2(v[i]);
            acc.x = fmaf(f.x, w, acc.x);
            acc.y = fmaf(f.y, w, acc.y);
        }
    }

    // bias + LN + ReLU
    float2 bb = ((const float2*)b1)[lane];
    acc.x += bb.x; acc.y += bb.y;
    float s = acc.x + acc.y;
    for (int off = 32; off; off >>= 1) s += __shfl_xor(s, off);
    float mu = s * (1.0f / 128.0f);
    float dx = acc.x - mu, dy = acc.y - mu;
    float q = dx * dx + dy * dy;
    for (int off = 32; off; off >>= 1) q += __shfl_xor(q, off);
    float rstd = rsqrtf(q * (1.0f / 128.0f) + 1e-5f);
    float2 gg = ((const float2*)g1)[lane];
    float2 be = ((const float2*)beta1)[lane];
    float ox = fmaxf(fmaf(dx * rstd, gg.x, be.x), 0.0f);
    float oy = fmaxf(fmaf(dy * rstd, gg.y, be.y), 0.0f);

    // 128x64 matvec via LDS broadcast; lane owns output col = lane
    ((float2*)&lds[wave][0])[lane] = make_float2(ox, oy);
    float o = 0.0f;
#pragma unroll 8
    for (int k = 0; k < K_DIM; k += 4) {
        float4 vv = *(const float4*)&lds[wave][k];
        o = fmaf(vv.x, W2[(size_t)(k + 0) * 64 + lane], o);
        o = fmaf(vv.y, W2[(size_t)(k + 1) * 64 + lane], o);
        o = fmaf(vv.z, W2[(size_t)(k + 2) * 64 + lane], o);
        o = fmaf(vv.w, W2[(size_t)(k + 3) * 64 + lane], o);
    }
    h3[(size_t)node * 64 + lane] = __float2half(o);
}

// ---------- gather2 fused: agg(h3) -> +b2 -> LN -> ReLU -> L2 -> out ----------
__global__ __launch_bounds__(256) void gather2_fused_kernel(
    const __half* __restrict__ h3, const float* __restrict__ dinv,
    const int* __restrict__ row_ptr, const int* __restrict__ counts,
    const int* __restrict__ partials, const unsigned int* __restrict__ edges,
    const float* __restrict__ b2, const float* __restrict__ g2,
    const float* __restrict__ beta2, float* __restrict__ out, int N) {
    int wave = threadIdx.x >> 6;
    int lane = threadIdx.x & 63;
    int node = blockIdx.x * 4 + wave;
    if (node >= N) return;

    float dd = dinv[node];
    float acc = __half2float(h3[(size_t)node * 64 + lane]) * dd * dd;

    int end = row_ptr[node] + partials[node >> 8];
    int beg = end - counts[node];
    beg = __builtin_amdgcn_readfirstlane(beg);
    end = __builtin_amdgcn_readfirstlane(end);

    int e = beg;
    for (; e + 16 <= end; e += 16) {
        unsigned int rec[16];
#pragma unroll
        for (int i = 0; i < 16; ++i) rec[i] = edges[e + i];
        __half v[16];
#pragma unroll
        for (int i = 0; i < 16; ++i)
            v[i] = h3[(size_t)(rec[i] & 0xFFFFu) * 64 + lane];
#pragma unroll
        for (int i = 0; i < 16; ++i)
            acc = fmaf(__half2float(v[i]), wbits(rec[i]), acc);
    }
    for (; e < end; e += 8) {
        unsigned int rec[8];
#pragma unroll
        for (int i = 0; i < 8; ++i) rec[i] = edges[e + i];
        __half v[8];
#pragma unroll
        for (int i = 0; i < 8; ++i)
            v[i] = h3[(size_t)(rec[i] & 0xFFFFu) * 64 + lane];
#pragma unroll
        for (int i = 0; i < 8; ++i) {
            float w = (e + i < end) ? wbits(rec[i]) : 0.0f;
            acc = fmaf(__half2float(v[i]), w, acc);
        }
    }

    float v = acc + b2[lane];
    float s = v;
    for (int off = 32; off; off >>= 1) s += __shfl_xor(s, off);
    float mu = s * (1.0f / 64.0f);
    float d = v - mu;
    float q = d * d;
    for (int off = 32; off; off >>= 1) q += __shfl_xor(q, off);
    float rstd = rsqrtf(q * (1.0f / 64.0f) + 1e-5f);
    float o = fmaxf(fmaf(d * rstd, g2[lane], beta2[lane]), 0.0f);
    float q2 = o * o;
    for (int off = 32; off; off >>= 1) q2 += __shfl_xor(q2, off);
    float nrm = sqrtf(q2);
    out[(size_t)node * 64 + lane] = o / fmaxf(nrm, 1e-12f);
}

extern "C" void kernel_launch(void* const* d_in, const int* in_sizes, int n_in,
                              void* d_out, int out_size, void* d_ws, size_t ws_size,
                              hipStream_t stream) {
    const float* x     = (const float*)d_in[0];
    const int*   ei    = (const int*)d_in[1];
    const float* W1    = (const float*)d_in[2];
    const float* b1    = (const float*)d_in[3];
    const float* g1    = (const float*)d_in[4];
    const float* beta1 = (const float*)d_in[5];
    const float* W2    = (const float*)d_in[6];
    const float* b2    = (const float*)d_in[7];
    const float* g2    = (const float*)d_in[8];
    const float* beta2 = (const float*)d_in[9];

    const int N = in_sizes[0] / 128;
    const int E = in_sizes[1] / 2;
    const int* src = ei;       // edge_index[0]
    const int* dst = ei + E;   // edge_index[1]
    float* out = (float*)d_out;

    // Workspace (~23 MB)
    char* p = (char*)d_ws;
    auto alloc = [&](size_t bytes) { char* r = p; p += (bytes + 255) & ~(size_t)255; return r; };
    int*          counts   = (int*)alloc((size_t)N * 4);
    int*          row_ptr  = (int*)alloc((size_t)N * 4);
    int*          partials = (int*)alloc(256 * 4);
    int*          done     = (int*)alloc(256);
    float*        dinv     = (float*)alloc((size_t)N * 4);
    unsigned int* edges    = (unsigned int*)alloc(((size_t)E + 64) * 4);  // +pad
    _Float16*     WT       = (_Float16*)alloc(128 * 128 * 2);
    __half*       h1       = (__half*)alloc((size_t)N * 128 * 2);
    __half*       h3       = (__half*)alloc((size_t)N * 64 * 2);

    const int nb_nodes = (N + 255) / 256;       // 196 chunks (<= 256)
    const int nb_edges = (E + 255) / 256;
    const int nb_wave_nodes = (N + 3) / 4;

    // 1) prep: zero counts/done/pad + WT transpose
    prep_kernel<<<nb_nodes, 256, 0, stream>>>(counts, done, edges, W1, WT, N, E);
    // 2) hist (4 edges/thread)
    hist_kernel<<<(E + 1023) / 1024, 256, 0, stream>>>(dst, counts, E);
    // 3) scan + dinv + last-block partials finalize
    scan_block_kernel<<<nb_nodes, 256, 0, stream>>>(counts, row_ptr, partials, dinv,
                                                    done, N, nb_nodes);
    // 4) fill (nt record stores)
    fill_kernel<<<nb_edges, 256, 0, stream>>>(src, dst, dinv, row_ptr, partials, edges, E);
    // 5) layer 1 GEMM (MFMA, f16 out)
    gemm1_mfma_kernel<<<(N + 63) / 64, 256, 0, stream>>>(x, WT, h1, N);
    // 6) layer 1 aggregate + LN + ReLU + layer 2 GEMM (fused)
    gather1_fused_kernel<<<nb_wave_nodes, 256, 0, stream>>>(
        h1, dinv, row_ptr, counts, partials, edges, b1, g1, beta1, W2, h3, N);
    // 7) layer 2 aggregate + LN + ReLU + L2 (fused)
    gather2_fused_kernel<<<nb_wave_nodes, 256, 0, stream>>>(
        h3, dinv, row_ptr, counts, partials, edges, b2, g2, beta2, out, N);
}

// Round 12
// 211.069 us; speedup vs baseline: 1.0444x; 1.0444x over previous
//
#include <hip/hip_runtime.h>
#include <hip/hip_fp16.h>

// GCN encoder on MI355X — FINAL (revert to round-10 best: 209.3 us).
// CSR (counting sort by dst) + fused gather aggregation.
// fp16 activations; 4-byte edge records {w:fp16 | src:u16} (N=50000 < 2^16);
// scalar (wave-uniform) record loads; ONE edge row per load instruction
// (multi-row loads regressed, round 8); main loop = 16 unpredicated row loads
// in flight (MLP), tail loop = 8 predicated. MFMA layer-1 GEMM; LN/ReLU/W2/L2
// epilogues fused into the gathers.
// Established floors (null probes): gather1 75us = per-XCD L2-miss concurrency
// floor (rounds 8/10/11); cooperative grid.sync ~70us/sync (round 9); launch
// compression regresses (rounds 9/11); XCD channel slicing regresses (round 6).

#define K_DIM 128

typedef _Float16 f16x8 __attribute__((ext_vector_type(8)));
typedef _Float16 f16x4 __attribute__((ext_vector_type(4)));
typedef float f32x4 __attribute__((ext_vector_type(4)));

__device__ __forceinline__ float wbits(unsigned int r) {
    return __half2float(__ushort_as_half((unsigned short)(r >> 16)));
}

// ---------- CSR build ----------
__global__ __launch_bounds__(256) void hist_kernel(const int* __restrict__ dst,
                                                   int* counts, int E) {
    int i = blockIdx.x * 256 + threadIdx.x;
    if (i < E) atomicAdd(&counts[dst[i]], 1);
}

__global__ __launch_bounds__(256) void scan_block_kernel(const int* __restrict__ counts,
                                                         int* row_ptr, int* partials,
                                                         float* dinv, int N) {
    __shared__ int sm[256];
    int t = threadIdx.x;
    int i = blockIdx.x * 256 + t;
    int v = (i < N) ? counts[i] : 0;
    if (i < N) dinv[i] = rsqrtf((float)(v + 1));
    sm[t] = v;
    __syncthreads();
    for (int off = 1; off < 256; off <<= 1) {
        int add = (t >= off) ? sm[t - off] : 0;
        __syncthreads();
        sm[t] += add;
        __syncthreads();
    }
    if (i < N) row_ptr[i] = sm[t] - v;  // block-local exclusive
    if (t == 255) partials[blockIdx.x] = sm[255];
}

__global__ __launch_bounds__(256) void scan_partials_kernel(int* partials, int NB) {
    __shared__ int sm[256];
    int t = threadIdx.x;
    int v = (t < NB) ? partials[t] : 0;
    sm[t] = v;
    __syncthreads();
    for (int off = 1; off < 256; off <<= 1) {
        int add = (t >= off) ? sm[t - off] : 0;
        __syncthreads();
        sm[t] += add;
        __syncthreads();
    }
    if (t < NB) partials[t] = sm[t] - v;  // exclusive
}

// fill: row_ptr[d] is a block-local cursor; global pos = cursor + partials[d>>8].
__global__ __launch_bounds__(256) void fill_kernel(const int* __restrict__ src,
                                                   const int* __restrict__ dst,
                                                   const float* __restrict__ dinv,
                                                   int* row_ptr,
                                                   const int* __restrict__ partials,
                                                   unsigned int* edges, int E) {
    int i = blockIdx.x * 256 + threadIdx.x;
    if (i < E) {
        int d = dst[i];
        int s = src[i];
        int pos = atomicAdd(&row_ptr[d], 1) + partials[d >> 8];
        float w = dinv[s] * dinv[d];
        unsigned int rec = ((unsigned int)__half_as_ushort(__float2half_rn(w)) << 16)
                         | (unsigned int)s;
        edges[pos] = rec;
    }
}

// ---------- W1 -> W1^T fp16 ----------
__global__ __launch_bounds__(256) void wt_prep_kernel(const float* __restrict__ W1,
                                                      _Float16* __restrict__ WT) {
    int idx = blockIdx.x * 256 + threadIdx.x;
    if (idx < 128 * 128) {
        int k = idx >> 7, j = idx & 127;
        WT[j * 128 + k] = (_Float16)W1[idx];
    }
}

// ---------- GEMM1 (MFMA): h1 = X @ W1, f16 out ----------
__global__ __launch_bounds__(256) void gemm1_mfma_kernel(const float* __restrict__ X,
                                                         const _Float16* __restrict__ WT,
                                                         __half* __restrict__ H, int N) {
    __shared__ _Float16 As[64][136];

    int row0 = blockIdx.x * 64;
    {
        int r = threadIdx.x >> 2;
        int c0 = (threadIdx.x & 3) * 32;
        int row = row0 + r;
        if (row < N) {
            const float4* srcp = (const float4*)(X + (size_t)row * 128 + c0);
#pragma unroll
            for (int i = 0; i < 8; ++i) {
                float4 v = srcp[i];
                f16x4 h = {(_Float16)v.x, (_Float16)v.y, (_Float16)v.z, (_Float16)v.w};
                *(f16x4*)&As[r][c0 + 4 * i] = h;
            }
        } else {
            f16x4 z = {};
#pragma unroll
            for (int i = 0; i < 8; ++i) *(f16x4*)&As[r][c0 + 4 * i] = z;
        }
    }
    __syncthreads();

    int wave = threadIdx.x >> 6;
    int lane = threadIdx.x & 63;
    int l15 = lane & 15;
    int k0 = (lane >> 4) * 8;
    int arow = wave * 16 + l15;

    f32x4 acc[8] = {};
#pragma unroll
    for (int ks = 0; ks < 4; ++ks) {
        f16x8 a = *(const f16x8*)&As[arow][ks * 32 + k0];
#pragma unroll
        for (int t = 0; t < 8; ++t) {
            f16x8 b = *(const f16x8*)(WT + (size_t)(t * 16 + l15) * 128 + ks * 32 + k0);
            acc[t] = __builtin_amdgcn_mfma_f32_16x16x32_f16(a, b, acc[t], 0, 0, 0);
        }
    }

    int rbase = row0 + wave * 16 + (lane >> 4) * 4;
#pragma unroll
    for (int t = 0; t < 8; ++t) {
#pragma unroll
        for (int r = 0; r < 4; ++r) {
            int row = rbase + r;
            if (row < N) H[(size_t)row * 128 + t * 16 + l15] = __float2half(acc[t][r]);
        }
    }
}

// ---------- gather1 fused: agg(h1) -> +b1 -> LN -> ReLU -> @W2 -> h3 (fp16) ----------
__global__ __launch_bounds__(256) void gather1_fused_kernel(
    const __half* __restrict__ h1, const float* __restrict__ dinv,
    const int* __restrict__ row_ptr, const int* __restrict__ counts,
    const int* __restrict__ partials, const unsigned int* __restrict__ edges,
    const float* __restrict__ b1, const float* __restrict__ g1,
    const float* __restrict__ beta1, const float* __restrict__ W2,
    __half* __restrict__ h3, int N) {
    __shared__ float lds[4][K_DIM];
    int wave = threadIdx.x >> 6;
    int lane = threadIdx.x & 63;
    int node = blockIdx.x * 4 + wave;
    if (node >= N) return;

    float dd = dinv[node];
    float2 acc = __half22float2(((const __half2*)(h1 + (size_t)node * 128))[lane]);
    acc.x *= dd * dd; acc.y *= dd * dd;

    int end = row_ptr[node] + partials[node >> 8];
    int beg = end - counts[node];
    beg = __builtin_amdgcn_readfirstlane(beg);
    end = __builtin_amdgcn_readfirstlane(end);

    int e = beg;
    // main: 16 unpredicated row loads in flight
    for (; e + 16 <= end; e += 16) {
        unsigned int rec[16];
#pragma unroll
        for (int i = 0; i < 16; ++i) rec[i] = edges[e + i];   // uniform -> s_load
        __half2 v[16];
#pragma unroll
        for (int i = 0; i < 16; ++i)
            v[i] = ((const __half2*)(h1 + (size_t)(rec[i] & 0xFFFFu) * 128))[lane];
#pragma unroll
        for (int i = 0; i < 16; ++i) {
            float w = wbits(rec[i]);
            float2 f = __half22float2(v[i]);
            acc.x = fmaf(f.x, w, acc.x);
            acc.y = fmaf(f.y, w, acc.y);
        }
    }
    // tail: 8-wide, predicated (pad rows are zero-weighted)
    for (; e < end; e += 8) {
        unsigned int rec[8];
#pragma unroll
        for (int i = 0; i < 8; ++i) rec[i] = edges[e + i];
        __half2 v[8];
#pragma unroll
        for (int i = 0; i < 8; ++i)
            v[i] = ((const __half2*)(h1 + (size_t)(rec[i] & 0xFFFFu) * 128))[lane];
#pragma unroll
        for (int i = 0; i < 8; ++i) {
            float w = (e + i < end) ? wbits(rec[i]) : 0.0f;
            float2 f = __half22float2(v[i]);
            acc.x = fmaf(f.x, w, acc.x);
            acc.y = fmaf(f.y, w, acc.y);
        }
    }

    // bias + LN + ReLU
    float2 bb = ((const float2*)b1)[lane];
    acc.x += bb.x; acc.y += bb.y;
    float s = acc.x + acc.y;
    for (int off = 32; off; off >>= 1) s += __shfl_xor(s, off);
    float mu = s * (1.0f / 128.0f);
    float dx = acc.x - mu, dy = acc.y - mu;
    float q = dx * dx + dy * dy;
    for (int off = 32; off; off >>= 1) q += __shfl_xor(q, off);
    float rstd = rsqrtf(q * (1.0f / 128.0f) + 1e-5f);
    float2 gg = ((const float2*)g1)[lane];
    float2 be = ((const float2*)beta1)[lane];
    float ox = fmaxf(fmaf(dx * rstd, gg.x, be.x), 0.0f);
    float oy = fmaxf(fmaf(dy * rstd, gg.y, be.y), 0.0f);

    // 128x64 matvec via LDS broadcast; lane owns output col = lane
    ((float2*)&lds[wave][0])[lane] = make_float2(ox, oy);
    float o = 0.0f;
#pragma unroll 8
    for (int k = 0; k < K_DIM; k += 4) {
        float4 vv = *(const float4*)&lds[wave][k];
        o = fmaf(vv.x, W2[(size_t)(k + 0) * 64 + lane], o);
        o = fmaf(vv.y, W2[(size_t)(k + 1) * 64 + lane], o);
        o = fmaf(vv.z, W2[(size_t)(k + 2) * 64 + lane], o);
        o = fmaf(vv.w, W2[(size_t)(k + 3) * 64 + lane], o);
    }
    h3[(size_t)node * 64 + lane] = __float2half(o);
}

// ---------- gather2 fused: agg(h3) -> +b2 -> LN -> ReLU -> L2 -> out ----------
__global__ __launch_bounds__(256) void gather2_fused_kernel(
    const __half* __restrict__ h3, const float* __restrict__ dinv,
    const int* __restrict__ row_ptr, const int* __restrict__ counts,
    const int* __restrict__ partials, const unsigned int* __restrict__ edges,
    const float* __restrict__ b2, const float* __restrict__ g2,
    const float* __restrict__ beta2, float* __restrict__ out, int N) {
    int wave = threadIdx.x >> 6;
    int lane = threadIdx.x & 63;
    int node = blockIdx.x * 4 + wave;
    if (node >= N) return;

    float dd = dinv[node];
    float acc = __half2float(h3[(size_t)node * 64 + lane]) * dd * dd;

    int end = row_ptr[node] + partials[node >> 8];
    int beg = end - counts[node];
    beg = __builtin_amdgcn_readfirstlane(beg);
    end = __builtin_amdgcn_readfirstlane(end);

    int e = beg;
    for (; e + 16 <= end; e += 16) {
        unsigned int rec[16];
#pragma unroll
        for (int i = 0; i < 16; ++i) rec[i] = edges[e + i];
        __half v[16];
#pragma unroll
        for (int i = 0; i < 16; ++i)
            v[i] = h3[(size_t)(rec[i] & 0xFFFFu) * 64 + lane];
#pragma unroll
        for (int i = 0; i < 16; ++i)
            acc = fmaf(__half2float(v[i]), wbits(rec[i]), acc);
    }
    for (; e < end; e += 8) {
        unsigned int rec[8];
#pragma unroll
        for (int i = 0; i < 8; ++i) rec[i] = edges[e + i];
        __half v[8];
#pragma unroll
        for (int i = 0; i < 8; ++i)
            v[i] = h3[(size_t)(rec[i] & 0xFFFFu) * 64 + lane];
#pragma unroll
        for (int i = 0; i < 8; ++i) {
            float w = (e + i < end) ? wbits(rec[i]) : 0.0f;
            acc = fmaf(__half2float(v[i]), w, acc);
        }
    }

    float v = acc + b2[lane];
    float s = v;
    for (int off = 32; off; off >>= 1) s += __shfl_xor(s, off);
    float mu = s * (1.0f / 64.0f);
    float d = v - mu;
    float q = d * d;
    for (int off = 32; off; off >>= 1) q += __shfl_xor(q, off);
    float rstd = rsqrtf(q * (1.0f / 64.0f) + 1e-5f);
    float o = fmaxf(fmaf(d * rstd, g2[lane], beta2[lane]), 0.0f);
    float q2 = o * o;
    for (int off = 32; off; off >>= 1) q2 += __shfl_xor(q2, off);
    float nrm = sqrtf(q2);
    out[(size_t)node * 64 + lane] = o / fmaxf(nrm, 1e-12f);
}

extern "C" void kernel_launch(void* const* d_in, const int* in_sizes, int n_in,
                              void* d_out, int out_size, void* d_ws, size_t ws_size,
                              hipStream_t stream) {
    const float* x     = (const float*)d_in[0];
    const int*   ei    = (const int*)d_in[1];
    const float* W1    = (const float*)d_in[2];
    const float* b1    = (const float*)d_in[3];
    const float* g1    = (const float*)d_in[4];
    const float* beta1 = (const float*)d_in[5];
    const float* W2    = (const float*)d_in[6];
    const float* b2    = (const float*)d_in[7];
    const float* g2    = (const float*)d_in[8];
    const float* beta2 = (const float*)d_in[9];

    const int N = in_sizes[0] / 128;
    const int E = in_sizes[1] / 2;
    const int* src = ei;       // edge_index[0]
    const int* dst = ei + E;   // edge_index[1]
    float* out = (float*)d_out;

    // Workspace (~23 MB)
    char* p = (char*)d_ws;
    auto alloc = [&](size_t bytes) { char* r = p; p += (bytes + 255) & ~(size_t)255; return r; };
    int*          counts   = (int*)alloc((size_t)N * 4);
    int*          row_ptr  = (int*)alloc((size_t)N * 4);
    int*          partials = (int*)alloc(256 * 4);
    float*        dinv     = (float*)alloc((size_t)N * 4);
    unsigned int* edges    = (unsigned int*)alloc(((size_t)E + 64) * 4);  // +pad
    _Float16*     WT       = (_Float16*)alloc(128 * 128 * 2);
    __half*       h1       = (__half*)alloc((size_t)N * 128 * 2);
    __half*       h3       = (__half*)alloc((size_t)N * 64 * 2);

    const int nb_nodes = (N + 255) / 256;
    const int nb_edges = (E + 255) / 256;
    const int nb_wave_nodes = (N + 3) / 4;

    // CSR build + dinv + packed 4-byte edge records (+ zeroed pad)
    hipMemsetAsync(counts, 0, (size_t)N * 4, stream);
    hipMemsetAsync(edges + E, 0, 64 * 4, stream);
    hist_kernel<<<nb_edges, 256, 0, stream>>>(dst, counts, E);
    scan_block_kernel<<<nb_nodes, 256, 0, stream>>>(counts, row_ptr, partials, dinv, N);
    scan_partials_kernel<<<1, 256, 0, stream>>>(partials, nb_nodes);
    fill_kernel<<<nb_edges, 256, 0, stream>>>(src, dst, dinv, row_ptr, partials, edges, E);

    // layer 1 GEMM (MFMA, f16 out)
    wt_prep_kernel<<<64, 256, 0, stream>>>(W1, WT);
    gemm1_mfma_kernel<<<(N + 63) / 64, 256, 0, stream>>>(x, WT, h1, N);

    // layer 1 aggregate + LN + ReLU + layer 2 GEMM (fused)
    gather1_fused_kernel<<<nb_wave_nodes, 256, 0, stream>>>(
        h1, dinv, row_ptr, counts, partials, edges, b1, g1, beta1, W2, h3, N);

    // layer 2 aggregate + LN + ReLU + L2 (fused)
    gather2_fused_kernel<<<nb_wave_nodes, 256, 0, stream>>>(
        h3, dinv, row_ptr, counts, partials, edges, b2, g2, beta2, out, N);
}